// Round 7
// baseline (56.968 us; speedup 1.0000x reference)
//
#include <hip/hip_runtime.h>
#include <math.h>

#define HS 8
#define E 12
#define NA 20
#define KC 4

typedef float f32x4 __attribute__((ext_vector_type(4)));
typedef short short8 __attribute__((ext_vector_type(8)));

// ---------------- Precomputed, batch-independent tables ----------------
__device__ float g_ET[4 * 54 * 54];   // exp(q_h(c1)·k_h(c2)/sqrt(3))
__device__ float g_VT[4 * 54 * 4];    // per-head v vectors (v0,v1,v2,1)
__device__ float g_abias[NA * 32];    // per-action folded score bias
__device__ float g_cb1f[128];         // folded ctx1 bias
__device__ __align__(16) short g_gsB[4 * 64 * 16];        // gs_w1 B-frags [t][lane][8hi,8lo]
__device__ __align__(16) short g_dpB[8 * 64 * 16];        // dp_w1 B-frags [s*4+t][lane][...]
__device__ __align__(16) short g_ctxB2[40 * 64 * 16];     // W' B-frags [s*8+tt][lane][...]
__device__ __align__(16) short g_WtB[8 * 64 * 16];        // Wt B-frags [s*2+t][lane][...]
// Inter-kernel features: [B][32] = attsum/len(12), enemy(12), 1/len, pad(7)=0
// (BSS zero-init; pads never written -> stay 0 forever)
__device__ __align__(16) float g_feat[65536 * 32];

__device__ __forceinline__ void split_bf16(float f, short& hi, short& lo) {
    unsigned u = __float_as_uint(f);
    unsigned r = (u + 0x7FFFu + ((u >> 16) & 1u)) >> 16;  // RNE to bf16
    hi = (short)r;
    float fh = __uint_as_float(r << 16);
    unsigned v = __float_as_uint(f - fh);
    unsigned r2 = (v + 0x7FFFu + ((v >> 16) & 1u)) >> 16;
    lo = (short)r2;
}

__device__ __forceinline__ void split8(const float* x, short8& hi, short8& lo) {
#pragma unroll
    for (int j = 0; j < 8; ++j) {
        short h, l;
        split_bf16(x[j], h, l);
        hi[j] = h; lo[j] = l;
    }
}

#define MFMA(a, b, c) __builtin_amdgcn_mfma_f32_16x16x32_bf16(a, b, c, 0, 0, 0)

__device__ __forceinline__ f32x4 mfma3(short8 ah, short8 al, const short* frag, f32x4 c) {
    const short8* bp = (const short8*)frag;
    short8 bh = bp[0], bl = bp[1];
    c = MFMA(ah, bh, c);
    c = MFMA(ah, bl, c);
    c = MFMA(al, bh, c);
    return c;
}

// W'[hid][k], k in 0..159
__device__ float wprime(int hid, int k, const float* ctx_w1, const float* out_w,
                        const float* out_b, const float* gs_w2, const float* dp_w2) {
    if (k < 12) {
        float s = 0.f;
        for (int i = 0; i < 12; ++i) s += ctx_w1[hid * 36 + i] * out_w[i * 12 + k];
        return s;
    } else if (k < 24) {
        return ctx_w1[hid * 36 + k];
    } else if (k == 24) {
        float s = 0.f;
        for (int i = 0; i < 12; ++i) s += ctx_w1[hid * 36 + i] * out_b[i];
        return 8.f * s;
    } else if (k < 32) {
        return 0.f;
    } else if (k < 96) {
        int u = k - 32;
        float s = 0.f;
        for (int c = 0; c < 6; ++c) s += ctx_w1[hid * 36 + 24 + c] * gs_w2[c * 64 + u];
        return s;
    } else {
        int u = k - 96;
        float s = 0.f;
        for (int c = 0; c < 6; ++c) s += ctx_w1[hid * 36 + 30 + c] * dp_w2[c * 64 + u];
        return s;
    }
}

__global__ void precompute_kernel(const float* __restrict__ card_emb,
                                  const int* __restrict__ aci,
                                  const float* __restrict__ ctx_w2,
                                  const float* __restrict__ ctx_b2,
                                  const float* __restrict__ sc_w1,
                                  const float* __restrict__ sc_b1,
                                  const float* __restrict__ in_w,
                                  const float* __restrict__ in_b,
                                  const float* __restrict__ ctx_w1,
                                  const float* __restrict__ ctx_b1,
                                  const float* __restrict__ dp_w1,
                                  const float* __restrict__ gs_w1,
                                  const float* __restrict__ gs_w2,
                                  const float* __restrict__ gs_b2,
                                  const float* __restrict__ dp_w2,
                                  const float* __restrict__ dp_b2,
                                  const float* __restrict__ out_w,
                                  const float* __restrict__ out_b) {
    const int O_ET = 11664, O_VT = O_ET + 216, O_GS = O_VT + 2048, O_DP = O_GS + 4096;
    const int O_CX = O_DP + 20480, O_WT = O_CX + 4096, O_AB = O_WT + 640, O_CB = O_AB + 128;
    int t = blockIdx.x * 256 + threadIdx.x;
    if (t < O_ET) {
        int h = t / 2916, rem = t % 2916;
        int c1 = rem / 54, c2 = rem % 54;
        float s = 0.f;
#pragma unroll
        for (int d = 0; d < 3; ++d) {
            float q = in_b[h * 3 + d], k = in_b[12 + h * 3 + d];
            for (int j = 0; j < 12; ++j) {
                q += in_w[(h * 3 + d) * 12 + j] * card_emb[c1 * 12 + j];
                k += in_w[(12 + h * 3 + d) * 12 + j] * card_emb[c2 * 12 + j];
            }
            s += q * k;
        }
        g_ET[t] = expf(s * 0.5773502691896258f);
    } else if (t < O_VT) {
        int t2 = t - O_ET;
        int h = t2 / 54, c = t2 % 54;
#pragma unroll
        for (int d = 0; d < 3; ++d) {
            float v = in_b[24 + h * 3 + d];
            for (int j = 0; j < 12; ++j)
                v += in_w[(24 + h * 3 + d) * 12 + j] * card_emb[c * 12 + j];
            g_VT[t2 * 4 + d] = v;
        }
        g_VT[t2 * 4 + 3] = 1.0f;
    } else if (t < O_GS) {
        int id = t - O_VT;
        int tt = id >> 9, lane = (id >> 3) & 63, j = id & 7;
        int g = lane >> 4, n = lane & 15;
        int k = 8 * g + j, col = 16 * tt + n;
        float wv = (k < 12) ? gs_w1[col * 12 + k] : 0.f;
        short hi, lo;
        split_bf16(wv, hi, lo);
        int base = ((tt << 6) + lane) << 4;
        g_gsB[base + j] = hi;
        g_gsB[base + 8 + j] = lo;
    } else if (t < O_DP) {
        int id = t - O_GS;
        int st = id >> 9, lane = (id >> 3) & 63, j = id & 7;
        int s = st >> 2, tt = st & 3;
        int g = lane >> 4, n = lane & 15;
        int k = 32 * s + 8 * g + j, col = 16 * tt + n;
        float wv = (k < 54) ? dp_w1[col * 54 + k] : 0.f;
        short hi, lo;
        split_bf16(wv, hi, lo);
        int base = ((st << 6) + lane) << 4;
        g_dpB[base + j] = hi;
        g_dpB[base + 8 + j] = lo;
    } else if (t < O_CX) {
        int id = t - O_DP;
        int st = id >> 9, lane = (id >> 3) & 63, j = id & 7;
        int s = st / 8, tt = st % 8;
        int g = lane >> 4, n = lane & 15;
        int k = 32 * s + 8 * g + j, col = 16 * tt + n;
        float wv = wprime(col, k, ctx_w1, out_w, out_b, gs_w2, dp_w2);
        short hi, lo;
        split_bf16(wv, hi, lo);
        int base = ((st << 6) + lane) << 4;
        g_ctxB2[base + j] = hi;
        g_ctxB2[base + 8 + j] = lo;
    } else if (t < O_WT) {
        int id = t - O_CX;
        int st = id >> 9, lane = (id >> 3) & 63, j = id & 7;
        int s = st >> 1, tt = st & 1;
        int g = lane >> 4, n = lane & 15;
        int k = 32 * s + 8 * g + j, col = 16 * tt + n;
        float wv = 0.f;
        for (int i = 0; i < 128; ++i) wv += sc_w1[col * 140 + i] * ctx_w2[i * 128 + k];
        short hi, lo;
        split_bf16(wv, hi, lo);
        int base = ((st << 6) + lane) << 4;
        g_WtB[base + j] = hi;
        g_WtB[base + 8 + j] = lo;
    } else if (t < O_AB) {
        int t2 = t - O_WT;
        int a = t2 >> 5, j = t2 & 31;
        float arep[E];
#pragma unroll
        for (int k2 = 0; k2 < E; ++k2) arep[k2] = 0.f;
        float cnt = 0.f;
#pragma unroll
        for (int c = 0; c < KC; ++c) {
            int idx = aci[a * KC + c];
            if (idx != 0) {
                cnt += 1.f;
#pragma unroll
                for (int k2 = 0; k2 < E; ++k2) arep[k2] += card_emb[idx * E + k2];
            }
        }
        float inv = 1.f / fmaxf(cnt, 1.f);
        float s = sc_b1[j];
#pragma unroll
        for (int k2 = 0; k2 < E; ++k2) s += sc_w1[j * 140 + 128 + k2] * (arep[k2] * inv);
        for (int i = 0; i < 128; ++i) s += sc_w1[j * 140 + i] * ctx_b2[i];
        g_abias[t2] = s;
    } else if (t < O_CB) {
        int hid = t - O_AB;
        float s = ctx_b1[hid];
        for (int c = 0; c < 6; ++c) {
            s += ctx_w1[hid * 36 + 24 + c] * gs_b2[c];
            s += ctx_w1[hid * 36 + 30 + c] * dp_b2[c];
        }
        g_cb1f[hid] = s;
    }
}

// ============ Kernel A: table-driven attention + enemy -> g_feat ============
// 1024 threads = 256 elements/block (quad map: el=tid>>2, head q=tid&3).
__global__ __launch_bounds__(1024) void featA_kernel(
    const int* __restrict__ hand_cards, const int* __restrict__ enemy_card,
    const int* __restrict__ hand_size, const float* __restrict__ enemy_emb) {
    __shared__ float sET[4 * 54 * 54];
    __shared__ __align__(16) float4 sV[4 * 54];
    __shared__ float sEN[54 * 12];

    int tid = threadIdx.x;
    for (int i = tid; i < 11664; i += 1024) sET[i] = g_ET[i];
    for (int i = tid; i < 864; i += 1024) ((float*)sV)[i] = g_VT[i];
    for (int i = tid; i < 648; i += 1024) sEN[i] = enemy_emb[i];
    __syncthreads();

    int q = tid & 3;
    int el = tid >> 2;
    int b = blockIdx.x * 256 + el;

    int hc[HS];
    {
        const int4* hp = (const int4*)(hand_cards + (size_t)b * HS);
        int4 h0 = hp[0], h1 = hp[1];
        hc[0] = h0.x; hc[1] = h0.y; hc[2] = h0.z; hc[3] = h0.w;
        hc[4] = h1.x; hc[5] = h1.y; hc[6] = h1.z; hc[7] = h1.w;
    }
    int ec = enemy_card[b];

    // masked v vectors (v0,v1,v2,1)*m_k
    float4 vv[HS];
#pragma unroll
    for (int k = 0; k < HS; ++k) {
        float4 v = sV[q * 54 + hc[k]];
        if (hc[k] == 0) v = make_float4(0.f, 0.f, 0.f, 0.f);
        vv[k] = v;
    }

    const float* eb = sET + q * 2916;
    float a0 = 0.f, a1 = 0.f, a2 = 0.f;
#pragma unroll
    for (int p = 0; p < HS; ++p) {
        const float* er = eb + hc[p] * 54;
        float n0 = 0.f, n1 = 0.f, n2 = 0.f, nw = 0.f;
#pragma unroll
        for (int k = 0; k < HS; ++k) {
            float e = er[hc[k]];
            n0 += e * vv[k].x;
            n1 += e * vv[k].y;
            n2 += e * vv[k].z;
            nw += e * vv[k].w;
        }
        float rw = 1.f / fmaxf(nw, 1e-30f);
        a0 += n0 * rw; a1 += n1 * rw; a2 += n2 * rw;
    }
    float invlen = 1.f / fmaxf((float)hand_size[b], 1.f);
    float* fr = g_feat + (size_t)b * 32;
    fr[3 * q + 0] = a0 * invlen;
    fr[3 * q + 1] = a1 * invlen;
    fr[3 * q + 2] = a2 * invlen;
    fr[12 + 3 * q + 0] = sEN[ec * 12 + 3 * q + 0];
    fr[12 + 3 * q + 1] = sEN[ec * 12 + 3 * q + 1];
    fr[12 + 3 * q + 2] = sEN[ec * 12 + 3 * q + 2];
    if (q == 0) fr[24] = invlen;
}

#define FENCE() do { asm volatile("s_waitcnt lgkmcnt(0)" ::: "memory"); \
                     __builtin_amdgcn_sched_barrier(0); } while (0)

// ============ Kernel B: gs1/dp1/ctx1/Wt MFMA chain + score ============
// 256 threads = 4 waves = 64 elements; wave handles 16 (el = 16w + n).
__global__ __launch_bounds__(256) void scoreB_kernel(
    const float* __restrict__ game_state, const float* __restrict__ discard,
    const int* __restrict__ num_valid, const float* __restrict__ gs_b1,
    const float* __restrict__ dp_b1, const float* __restrict__ sc_w2,
    const float* __restrict__ sc_b2, float* __restrict__ out) {
    __shared__ __align__(16) float sA[4 * 16 * 132];  // per-wave staging, stride 132
    __shared__ __align__(16) float sAB[NA * 36];
    __shared__ __align__(16) float sW2[32];
    __shared__ float sCB[128];
    __shared__ float sGSB[64];
    __shared__ float sDPB[64];

    int tid = threadIdx.x;
    for (int i = tid; i < NA * 36; i += 256) {
        int a = i / 36, c = i % 36;
        sAB[i] = (c < 32) ? g_abias[a * 32 + c] : 0.f;
    }
    if (tid >= 160 && tid < 192) sW2[tid - 160] = sc_w2[tid - 160];
    if (tid < 128) sCB[tid] = g_cb1f[tid];
    if (tid >= 192 && tid < 256) sGSB[tid - 192] = gs_b1[tid - 192];
    if (tid >= 128 && tid < 160) { sDPB[tid - 128] = dp_b1[tid - 128]; sDPB[tid - 96] = dp_b1[tid - 96]; }
    __syncthreads();

    int lane = tid & 63;
    int w = tid >> 6;
    int n = lane & 15, g = lane >> 4;
    size_t b2 = (size_t)blockIdx.x * 64 + (w << 4) + n;
    float* SA = sA + w * 2112;

    // ---- gs1 MFMA (K=32, k<12 valid) -> SA cols 0..63 ----
    {
        float xg[8];
#pragma unroll
        for (int j = 0; j < 8; ++j) {
            int k = 8 * g + j;
            xg[j] = (k < 12) ? game_state[b2 * 12 + k] : 0.f;
        }
        short8 xh, xl;
        split8(xg, xh, xl);
        f32x4 gacc[4];
#pragma unroll
        for (int t = 0; t < 4; ++t) {
            float bv = sGSB[16 * t + n];
            f32x4 cc = {bv, bv, bv, bv};
            gacc[t] = mfma3(xh, xl, &g_gsB[((t << 6) + lane) << 4], cc);
        }
#pragma unroll
        for (int t = 0; t < 4; ++t)
#pragma unroll
            for (int r = 0; r < 4; ++r)
                SA[(4 * g + r) * 132 + 16 * t + n] = fmaxf(gacc[t][r], 0.f);
    }
    // ---- dp1 MFMA (K=64) -> SA cols 64..127 ----
    {
        const float* drow = discard + b2 * 54;
        float xa[8], xb[8];
        {
            const float2* p = (const float2*)(drow + 8 * g);
            float2 v0 = p[0], v1 = p[1], v2 = p[2], v3 = p[3];
            xa[0] = v0.x; xa[1] = v0.y; xa[2] = v1.x; xa[3] = v1.y;
            xa[4] = v2.x; xa[5] = v2.y; xa[6] = v3.x; xa[7] = v3.y;
        }
#pragma unroll
        for (int j = 0; j < 8; ++j) {
            int k = 32 + 8 * g + j;
            xb[j] = (k < 54) ? drow[k] : 0.f;
        }
        short8 ah0, al0, ah1, al1;
        split8(xa, ah0, al0);
        split8(xb, ah1, al1);
        f32x4 dacc[4];
#pragma unroll
        for (int t = 0; t < 4; ++t) {
            float bv = sDPB[16 * t + n];
            f32x4 cc = {bv, bv, bv, bv};
            cc = mfma3(ah0, al0, &g_dpB[((t << 6) + lane) << 4], cc);
            cc = mfma3(ah1, al1, &g_dpB[(((4 + t) << 6) + lane) << 4], cc);
            dacc[t] = cc;
        }
#pragma unroll
        for (int t = 0; t < 4; ++t)
#pragma unroll
            for (int r = 0; r < 4; ++r)
                SA[(4 * g + r) * 132 + 64 + 16 * t + n] = fmaxf(dacc[t][r], 0.f);
    }
    FENCE();

    // ---- ctx1 MFMA (K=160): s=0 from g_feat, s=1..4 from SA ----
    f32x4 cacc[8];
#pragma unroll
    for (int tt = 0; tt < 8; ++tt) {
        float bv = sCB[16 * tt + n];
        f32x4 cc = {bv, bv, bv, bv};
        cacc[tt] = cc;
    }
    {
        const float4* fp = (const float4*)(g_feat + b2 * 32 + 8 * g);
        float4 f0 = fp[0], f1 = fp[1];
        float ca[8] = {f0.x, f0.y, f0.z, f0.w, f1.x, f1.y, f1.z, f1.w};
        short8 ah, al;
        split8(ca, ah, al);
#pragma unroll
        for (int tt = 0; tt < 8; ++tt)
            cacc[tt] = mfma3(ah, al, &g_ctxB2[((tt << 6) + lane) << 4], cacc[tt]);
    }
#pragma unroll
    for (int s = 1; s < 5; ++s) {
        const float4* ap = (const float4*)&SA[n * 132 + 32 * (s - 1) + 8 * g];
        float4 a0 = ap[0], a1 = ap[1];
        float ca[8] = {a0.x, a0.y, a0.z, a0.w, a1.x, a1.y, a1.z, a1.w};
        short8 ah, al;
        split8(ca, ah, al);
#pragma unroll
        for (int tt = 0; tt < 8; ++tt)
            cacc[tt] = mfma3(ah, al, &g_ctxB2[(((s * 8 + tt) << 6) + lane) << 4], cacc[tt]);
    }
    FENCE();
    // relu(h_ctx) -> SA cols 0..127
#pragma unroll
    for (int tt = 0; tt < 8; ++tt)
#pragma unroll
        for (int r = 0; r < 4; ++r)
            SA[(4 * g + r) * 132 + 16 * tt + n] = fmaxf(cacc[tt][r], 0.f);
    FENCE();

    // ---- Wt MFMA (K=128) ----
    f32x4 uacc[2];
    {
        f32x4 z = {0.f, 0.f, 0.f, 0.f};
        uacc[0] = z; uacc[1] = z;
    }
#pragma unroll
    for (int s = 0; s < 4; ++s) {
        const float4* ap = (const float4*)&SA[n * 132 + 32 * s + 8 * g];
        float4 a0 = ap[0], a1 = ap[1];
        float ha[8] = {a0.x, a0.y, a0.z, a0.w, a1.x, a1.y, a1.z, a1.w};
        short8 ah, al;
        split8(ha, ah, al);
#pragma unroll
        for (int t2 = 0; t2 < 2; ++t2)
            uacc[t2] = mfma3(ah, al, &g_WtB[(((s * 2 + t2) << 6) + lane) << 4], uacc[t2]);
    }
    FENCE();
#pragma unroll
    for (int t2 = 0; t2 < 2; ++t2)
#pragma unroll
        for (int r = 0; r < 4; ++r)
            SA[(4 * g + r) * 132 + 16 * t2 + n] = uacc[t2][r];
    FENCE();

    // ---- score layer ----
    {
        float uu[32];
        {
            const float4* up = (const float4*)&SA[n * 132];
#pragma unroll
            for (int j8 = 0; j8 < 8; ++j8) {
                float4 v = up[j8];
                uu[4 * j8 + 0] = v.x; uu[4 * j8 + 1] = v.y;
                uu[4 * j8 + 2] = v.z; uu[4 * j8 + 3] = v.w;
            }
        }
        int nva = num_valid[0];
        float sb2 = sc_b2[0];
#pragma unroll
        for (int t = 0; t < 5; ++t) {
            int a = g * 5 + t;
            const float4* ab = (const float4*)&sAB[a * 36];
            float s = sb2;
#pragma unroll
            for (int j8 = 0; j8 < 8; ++j8) {
                float4 av = ab[j8];
                float4 wv = ((const float4*)sW2)[j8];
                s += wv.x * fmaxf(uu[4 * j8 + 0] + av.x, 0.f);
                s += wv.y * fmaxf(uu[4 * j8 + 1] + av.y, 0.f);
                s += wv.z * fmaxf(uu[4 * j8 + 2] + av.z, 0.f);
                s += wv.w * fmaxf(uu[4 * j8 + 3] + av.w, 0.f);
            }
            out[b2 * NA + a] = (a < nva) ? s : -1.0e8f;
        }
    }
}

extern "C" void kernel_launch(void* const* d_in, const int* in_sizes, int n_in,
                              void* d_out, int out_size, void* d_ws, size_t ws_size,
                              hipStream_t stream) {
    const int* hand_cards = (const int*)d_in[0];
    const float* game_state = (const float*)d_in[1];
    const float* discard = (const float*)d_in[2];
    const int* enemy_card = (const int*)d_in[3];
    const int* hand_size = (const int*)d_in[4];
    const int* aci = (const int*)d_in[5];
    const int* num_valid = (const int*)d_in[6];
    const float* card_emb = (const float*)d_in[7];
    const float* enemy_emb = (const float*)d_in[8];
    const float* in_w = (const float*)d_in[9];
    const float* in_b = (const float*)d_in[10];
    const float* out_w = (const float*)d_in[11];
    const float* out_b = (const float*)d_in[12];
    const float* gs_w1 = (const float*)d_in[13];
    const float* gs_b1 = (const float*)d_in[14];
    const float* gs_w2 = (const float*)d_in[15];
    const float* gs_b2 = (const float*)d_in[16];
    const float* dp_w1 = (const float*)d_in[17];
    const float* dp_b1 = (const float*)d_in[18];
    const float* dp_w2 = (const float*)d_in[19];
    const float* dp_b2 = (const float*)d_in[20];
    const float* ctx_w1 = (const float*)d_in[21];
    const float* ctx_b1 = (const float*)d_in[22];
    const float* ctx_w2 = (const float*)d_in[23];
    const float* ctx_b2 = (const float*)d_in[24];
    const float* sc_w1 = (const float*)d_in[25];
    const float* sc_b1 = (const float*)d_in[26];
    const float* sc_w2 = (const float*)d_in[27];
    const float* sc_b2 = (const float*)d_in[28];

    int B = in_sizes[0] / HS;

    precompute_kernel<<<170, 256, 0, stream>>>(
        card_emb, aci, ctx_w2, ctx_b2, sc_w1, sc_b1, in_w, in_b, ctx_w1, ctx_b1,
        dp_w1, gs_w1, gs_w2, gs_b2, dp_w2, dp_b2, out_w, out_b);
    featA_kernel<<<B / 256, 1024, 0, stream>>>(hand_cards, enemy_card, hand_size,
                                               enemy_emb);
    scoreB_kernel<<<B / 64, 256, 0, stream>>>(game_state, discard, num_valid,
                                              gs_b1, dp_b1, sc_w2, sc_b2,
                                              (float*)d_out);
}